// Round 1
// baseline (575.248 us; speedup 1.0000x reference)
//
#include <hip/hip_runtime.h>

#define N_NODES 131072
#define HID 256
#define NC 64
#define NG 64
#define MAXL 4096

// ws layout in floats
#define WS_Q      0u          // 64*256
#define WS_QW     16384u      // 64*256
#define WS_QO     32768u      // 64*256  (Q @ WO^T)
#define WS_WF     49152u      // 256*256 (Wf[i][d] = sum_j WO[i][j]*WV[j][d])
#define WS_QB     114688u     // 64
#define WS_BVO    114752u     // 256
#define WS_STARTS 115008u     // 65 ints
#define WS_ASUM   115200u     // 64*64
#define WS_G      119296u     // 64*64*256
#define WS_A      1167872u    // 131072*64

// ---------------- setup kernels ----------------

__global__ __launch_bounds__(256) void k_q(const float* __restrict__ Qp,
    const float* __restrict__ WQ_w, const float* __restrict__ WQ_b,
    float* __restrict__ Q)
{
  const int c = blockIdx.x, d = threadIdx.x;
  float acc = WQ_b[d];
  #pragma unroll 4
  for (int k = 0; k < 256; k += 4) {
    float4 w = *(const float4*)&WQ_w[d * 256 + k];
    acc += Qp[c * 256 + k + 0] * w.x + Qp[c * 256 + k + 1] * w.y
         + Qp[c * 256 + k + 2] * w.z + Qp[c * 256 + k + 3] * w.w;
  }
  Q[c * 256 + d] = acc;
}

__global__ __launch_bounds__(256) void k_fold(const float* __restrict__ Q,
    const float* __restrict__ WK_w, const float* __restrict__ WK_b,
    const float* __restrict__ WO_w,
    float* __restrict__ QW, float* __restrict__ QO, float* __restrict__ qb)
{
  const int c = blockIdx.x, d = threadIdx.x;
  double aqw = 0.0;
  float aqo = 0.f;
  for (int j = 0; j < 256; ++j) {
    float qcj = Q[c * 256 + j];
    aqw += (double)qcj * (double)WK_w[j * 256 + d];   // coalesced over d
    aqo += qcj * WO_w[d * 256 + j];
  }
  QW[c * 256 + d] = (float)(aqw * 0.0625);  // 1/sqrt(256)
  QO[c * 256 + d] = aqo;
  if (d == 0) {
    double s = 0.0;
    for (int j = 0; j < 256; ++j) s += (double)Q[c * 256 + j] * (double)WK_b[j];
    qb[c] = (float)(s * 0.0625);
  }
}

__global__ __launch_bounds__(256) void k_wf(const float* __restrict__ WO_w,
    const float* __restrict__ WV_w, const float* __restrict__ WV_b,
    float* __restrict__ Wf, float* __restrict__ bvo)
{
  const int i = blockIdx.x, d = threadIdx.x;
  float acc = 0.f;
  for (int j = 0; j < 256; ++j)
    acc += WO_w[i * 256 + j] * WV_w[j * 256 + d];   // coalesced over d
  Wf[i * 256 + d] = acc;
  if (d == 0) {
    float s = 0.f;
    for (int j = 0; j < 256; ++j) s += WV_b[j] * WO_w[i * 256 + j];
    bvo[i] = s;
  }
}

__global__ void k_starts(const int* __restrict__ batch, int* __restrict__ starts)
{
  int t = threadIdx.x;
  if (t > 64) return;
  if (t == 0) { starts[0] = 0; return; }
  if (t == 64) { starts[64] = N_NODES; return; }
  int lo = 0, hi = N_NODES;
  while (lo < hi) {
    int mid = (lo + hi) >> 1;
    if (batch[mid] < t) lo = mid + 1; else hi = mid;
  }
  starts[t] = lo;
}

// ---------------- main pass 1: scores + softmax + argmax + mask ----------------
// tile: 64 nodes x 64 clusters, K=256 in chunks of 64

__global__ __launch_bounds__(256) void k_scores(const float* __restrict__ x,
    const int* __restrict__ batch, const float* __restrict__ qw,
    const float* __restrict__ qbv, const int* __restrict__ starts,
    float* __restrict__ Aout, float* __restrict__ out_arg, float* __restrict__ out_msk)
{
  __shared__ float xs[64 * 68];
  __shared__ float qs[64 * 68];
  __shared__ float ss[64 * 65 + 128];
  const int t = threadIdx.x;
  const int n0 = blockIdx.x * 64;
  const int tx = t & 15, ty = t >> 4;   // compute: clusters tx+16i, nodes ty+16j
  const int sr = t >> 4, sq = t & 15;   // staging

  float acc[4][4];
  #pragma unroll
  for (int j = 0; j < 4; ++j)
    #pragma unroll
    for (int i = 0; i < 4; ++i) acc[j][i] = 0.f;

  for (int kc = 0; kc < 4; ++kc) {
    const int k0 = kc * 64;
    #pragma unroll
    for (int u = 0; u < 4; ++u) {
      int row = sr + 16 * u;
      *(float4*)&xs[row * 68 + sq * 4] =
          *(const float4*)&x[(size_t)(n0 + row) * 256 + k0 + sq * 4];
      *(float4*)&qs[row * 68 + sq * 4] =
          *(const float4*)&qw[row * 256 + k0 + sq * 4];
    }
    __syncthreads();
    #pragma unroll
    for (int k4 = 0; k4 < 16; ++k4) {
      float4 xr[4], qr[4];
      #pragma unroll
      for (int j = 0; j < 4; ++j) xr[j] = *(const float4*)&xs[(ty + 16 * j) * 68 + k4 * 4];
      #pragma unroll
      for (int i = 0; i < 4; ++i) qr[i] = *(const float4*)&qs[(tx + 16 * i) * 68 + k4 * 4];
      #pragma unroll
      for (int j = 0; j < 4; ++j)
        #pragma unroll
        for (int i = 0; i < 4; ++i)
          acc[j][i] += xr[j].x * qr[i].x + xr[j].y * qr[i].y
                     + xr[j].z * qr[i].z + xr[j].w * qr[i].w;
    }
    __syncthreads();
  }

  // scores -> LDS with +qb
  #pragma unroll
  for (int j = 0; j < 4; ++j)
    #pragma unroll
    for (int i = 0; i < 4; ++i)
      ss[(ty + 16 * j) * 65 + (tx + 16 * i)] = acc[j][i] + qbv[tx + 16 * i];
  __syncthreads();

  if (t < 64) {
    float m = ss[t * 65];
    int am = 0;
    for (int c = 1; c < 64; ++c) {
      float v = ss[t * 65 + c];
      if (v > m) { m = v; am = c; }
    }
    float sum = 0.f;
    for (int c = 0; c < 64; ++c) sum += __expf(ss[t * 65 + c] - m);
    ss[64 * 65 + t] = 1.f / sum;
    ss[64 * 65 + 64 + t] = m;
    int n = n0 + t;
    int b = batch[n];
    int pos = n - starts[b];
    out_arg[b * MAXL + pos] = (float)am;
    out_msk[b * MAXL + pos] = 1.0f;
  }
  __syncthreads();

  // write softmax weights A[n][c], coalesced
  {
    int node = t >> 2, q = t & 3;
    float inv = ss[64 * 65 + node], m = ss[64 * 65 + 64 + node];
    #pragma unroll
    for (int u = 0; u < 4; ++u) {
      int c = q * 16 + u * 4;
      float4 v;
      v.x = __expf(ss[node * 65 + c + 0] - m) * inv;
      v.y = __expf(ss[node * 65 + c + 1] - m) * inv;
      v.z = __expf(ss[node * 65 + c + 2] - m) * inv;
      v.w = __expf(ss[node * 65 + c + 3] - m) * inv;
      *(float4*)&Aout[(size_t)(n0 + node) * 64 + c] = v;
    }
  }
}

// ---------------- main pass 2: G_b = A_b^T X_b, asum_b = sum_n a_n ----------------
// grid: 64 graphs x 4 d-slices x 4 node-chunk strides

__global__ __launch_bounds__(256) void k_gacc(const float* __restrict__ x,
    const float* __restrict__ Ain, const int* __restrict__ starts,
    float* __restrict__ G, float* __restrict__ asum)
{
  __shared__ float as_[64 * 68];
  __shared__ float xs[64 * 68];
  const int t = threadIdx.x;
  const int b = blockIdx.x >> 4;
  const int ds = ((blockIdx.x >> 2) & 3) * 64;
  const int nc = blockIdx.x & 3;
  const int s0 = starts[b], s1 = starts[b + 1];
  const int tx = t & 15, ty = t >> 4;   // c = tx*4+i, d = ds + ty*4+j
  const int sr = t >> 2, sq = t & 3;

  float acc[4][4];
  float asum4[4] = {0.f, 0.f, 0.f, 0.f};
  #pragma unroll
  for (int i = 0; i < 4; ++i)
    #pragma unroll
    for (int j = 0; j < 4; ++j) acc[i][j] = 0.f;

  for (int base = s0 + nc * 64; base < s1; base += 256) {
    int row = base + sr;
    int rx = row < s1 ? row : (s1 - 1);
    #pragma unroll
    for (int u = 0; u < 4; ++u) {
      float4 av = make_float4(0.f, 0.f, 0.f, 0.f);
      if (row < s1) av = *(const float4*)&Ain[(size_t)row * 64 + sq * 16 + u * 4];
      *(float4*)&as_[sr * 68 + sq * 16 + u * 4] = av;
      *(float4*)&xs[sr * 68 + sq * 16 + u * 4] =
          *(const float4*)&x[(size_t)rx * 256 + ds + sq * 16 + u * 4];
    }
    __syncthreads();
    #pragma unroll 4
    for (int r = 0; r < 64; ++r) {
      float4 av = *(const float4*)&as_[r * 68 + tx * 4];
      float4 xv = *(const float4*)&xs[r * 68 + ty * 4];
      acc[0][0] += av.x * xv.x; acc[0][1] += av.x * xv.y; acc[0][2] += av.x * xv.z; acc[0][3] += av.x * xv.w;
      acc[1][0] += av.y * xv.x; acc[1][1] += av.y * xv.y; acc[1][2] += av.y * xv.z; acc[1][3] += av.y * xv.w;
      acc[2][0] += av.z * xv.x; acc[2][1] += av.z * xv.y; acc[2][2] += av.z * xv.z; acc[2][3] += av.z * xv.w;
      acc[3][0] += av.w * xv.x; acc[3][1] += av.w * xv.y; acc[3][2] += av.w * xv.z; acc[3][3] += av.w * xv.w;
      asum4[0] += av.x; asum4[1] += av.y; asum4[2] += av.z; asum4[3] += av.w;
    }
    __syncthreads();
  }

  #pragma unroll
  for (int i = 0; i < 4; ++i)
    #pragma unroll
    for (int j = 0; j < 4; ++j)
      atomicAdd(&G[(size_t)b * 16384 + (tx * 4 + i) * 256 + ds + ty * 4 + j], acc[i][j]);
  if (((blockIdx.x >> 2) & 3) == 0 && ty == 0) {
    #pragma unroll
    for (int i = 0; i < 4; ++i) atomicAdd(&asum[b * 64 + tx * 4 + i], asum4[i]);
  }
}

// ---------------- finalize: out = relu(qo + G@Wf^T + asum*bvo + WO_b) ----------------

__global__ __launch_bounds__(256) void k_final(const float* __restrict__ G,
    const float* __restrict__ Wf, const float* __restrict__ qo,
    const float* __restrict__ asum, const float* __restrict__ bvo,
    const float* __restrict__ WO_b, float* __restrict__ out)
{
  __shared__ float gs[64 * 68];
  __shared__ float wfs[64 * 68];
  const int t = threadIdx.x;
  const int b = blockIdx.x >> 2;
  const int is = (blockIdx.x & 3) * 64;
  const int tx = t & 15, ty = t >> 4;   // c = ty+16j, i = is + tx+16u
  const int sr = t >> 4, sq = t & 15;

  float acc[4][4];
  #pragma unroll
  for (int j = 0; j < 4; ++j)
    #pragma unroll
    for (int u = 0; u < 4; ++u) acc[j][u] = 0.f;

  for (int kc = 0; kc < 4; ++kc) {
    const int k0 = kc * 64;
    #pragma unroll
    for (int u = 0; u < 4; ++u) {
      int row = sr + 16 * u;
      *(float4*)&gs[row * 68 + sq * 4] =
          *(const float4*)&G[(size_t)b * 16384 + row * 256 + k0 + sq * 4];
      *(float4*)&wfs[row * 68 + sq * 4] =
          *(const float4*)&Wf[(size_t)(is + row) * 256 + k0 + sq * 4];
    }
    __syncthreads();
    #pragma unroll
    for (int k4 = 0; k4 < 16; ++k4) {
      float4 gr[4], wr[4];
      #pragma unroll
      for (int j = 0; j < 4; ++j) gr[j] = *(const float4*)&gs[(ty + 16 * j) * 68 + k4 * 4];
      #pragma unroll
      for (int u = 0; u < 4; ++u) wr[u] = *(const float4*)&wfs[(tx + 16 * u) * 68 + k4 * 4];
      #pragma unroll
      for (int j = 0; j < 4; ++j)
        #pragma unroll
        for (int u = 0; u < 4; ++u)
          acc[j][u] += gr[j].x * wr[u].x + gr[j].y * wr[u].y
                     + gr[j].z * wr[u].z + gr[j].w * wr[u].w;
    }
    __syncthreads();
  }

  #pragma unroll
  for (int j = 0; j < 4; ++j)
    #pragma unroll
    for (int u = 0; u < 4; ++u) {
      int c = ty + 16 * j, i = is + tx + 16 * u;
      float v = acc[j][u] + qo[c * 256 + i] + asum[b * 64 + c] * bvo[i] + WO_b[i];
      out[(size_t)b * 16384 + c * 256 + i] = fmaxf(v, 0.f);
    }
}

// ---------------- launch ----------------

extern "C" void kernel_launch(void* const* d_in, const int* in_sizes, int n_in,
                              void* d_out, int out_size, void* d_ws, size_t ws_size,
                              hipStream_t stream) {
  const float* x    = (const float*)d_in[0];
  const int*   batch= (const int*)d_in[1];
  const float* Qp   = (const float*)d_in[2];
  const float* WQ_w = (const float*)d_in[3];
  const float* WQ_b = (const float*)d_in[4];
  const float* WK_w = (const float*)d_in[5];
  const float* WK_b = (const float*)d_in[6];
  const float* WV_w = (const float*)d_in[7];
  const float* WV_b = (const float*)d_in[8];
  const float* WO_w = (const float*)d_in[9];
  const float* WO_b = (const float*)d_in[10];

  float* ws   = (float*)d_ws;
  float* Q    = ws + WS_Q;
  float* QW   = ws + WS_QW;
  float* QO   = ws + WS_QO;
  float* Wf   = ws + WS_WF;
  float* qb   = ws + WS_QB;
  float* bvo  = ws + WS_BVO;
  int*   starts = (int*)(ws + WS_STARTS);
  float* asum = ws + WS_ASUM;
  float* G    = ws + WS_G;
  float* A    = ws + WS_A;

  float* out     = (float*)d_out;                 // [64][64][256]
  float* out_arg = out + 64 * 64 * 256;           // [64][4096]
  float* out_msk = out_arg + 64 * 4096;           // [64][4096]

  // zero-init: G, asum, argmax+mask region of d_out
  hipMemsetAsync(G, 0, (size_t)64 * 16384 * 4, stream);
  hipMemsetAsync(asum, 0, (size_t)64 * 64 * 4, stream);
  hipMemsetAsync(out_arg, 0, (size_t)2 * 64 * 4096 * 4, stream);

  k_q<<<64, 256, 0, stream>>>(Qp, WQ_w, WQ_b, Q);
  k_wf<<<256, 256, 0, stream>>>(WO_w, WV_w, WV_b, Wf, bvo);
  k_starts<<<1, 128, 0, stream>>>(batch, starts);
  k_fold<<<64, 256, 0, stream>>>(Q, WK_w, WK_b, WO_w, QW, QO, qb);

  k_scores<<<N_NODES / 64, 256, 0, stream>>>(x, batch, QW, qb, starts, A, out_arg, out_msk);
  k_gacc<<<64 * 16, 256, 0, stream>>>(x, A, starts, G, asum);
  k_final<<<64 * 4, 256, 0, stream>>>(G, Wf, QO, asum, bvo, WO_b, out);
}